// Round 3
// baseline (276.655 us; speedup 1.0000x reference)
//
#include <hip/hip_runtime.h>

#define BB 256
#define NP 12
#define TT 20
#define DD 512
#define EPS_A 1e-6f
#define EPS_BN 1e-5f
#define THR2 (150.0f * 150.0f)
#define PA 520   // xg LDS pitch (ushorts): 1040 B, 16B-aligned, 2-way bank alias (free)
#define PY 516   // y1 LDS pitch (floats): +4 shift breaks epilogue write conflicts

typedef __attribute__((ext_vector_type(8))) short shortx8;
typedef __attribute__((ext_vector_type(4))) float floatx4;

static __device__ __forceinline__ ushort f2bf(float f) {
    unsigned x = __float_as_uint(f);
    return (ushort)((x + 0x7fffu + ((x >> 16) & 1u)) >> 16);  // RNE
}

// ---------------------------------------------------------------------------
// Prep: W1,W2 -> bf16 ; fold BN into per-d scale/shift
// ---------------------------------------------------------------------------
__global__ __launch_bounds__(256) void k_prep(
    const float* __restrict__ W1, const float* __restrict__ W2,
    const float* __restrict__ b1, const float* __restrict__ g1,
    const float* __restrict__ beta1, const float* __restrict__ m1, const float* __restrict__ v1,
    const float* __restrict__ b2, const float* __restrict__ g2,
    const float* __restrict__ beta2, const float* __restrict__ m2, const float* __restrict__ v2,
    ushort* __restrict__ wb1, ushort* __restrict__ wb2,
    float* __restrict__ s1, float* __restrict__ t1,
    float* __restrict__ s2, float* __restrict__ t2) {
    int bid = blockIdx.x, t = threadIdx.x;
    if (bid < 128) {  // cast 131072 float4 (W1 then W2), 4 per thread
        int idx = bid * 256 + t;
        #pragma unroll
        for (int u = 0; u < 4; u++) {
            int i = idx + u * 32768;
            float4 f = (i < 65536) ? ((const float4*)W1)[i] : ((const float4*)W2)[i - 65536];
            ushort4 o;
            o.x = f2bf(f.x); o.y = f2bf(f.y); o.z = f2bf(f.z); o.w = f2bf(f.w);
            if (i < 65536) *(ushort4*)(wb1 + (long)i * 4) = o;
            else           *(ushort4*)(wb2 + (long)(i - 65536) * 4) = o;
        }
    } else {
        for (int d = t; d < DD; d += 256) {
            float sa = g1[d] * rsqrtf(v1[d] + EPS_BN);
            s1[d] = sa; t1[d] = (b1[d] - m1[d]) * sa + beta1[d];
            float sb = g2[d] * rsqrtf(v2[d] + EPS_BN);
            s2[d] = sb; t2[d] = (b2[d] - m2[d]) * sb + beta2[d];
        }
    }
}

// ---------------------------------------------------------------------------
// Copy over skip-free index space (rows with t != 19 only; gemm2 writes t==19)
// ---------------------------------------------------------------------------
static __device__ __forceinline__ long remap(long j) {
    long rp = j >> 7;                       // pruned row index (19 rows/frame)
    long row = (rp / 19) * TT + rp % 19;    // actual row (20 rows/frame)
    return (row << 7) | (j & 127);
}

static __device__ __forceinline__ void copy_body(long tid, long nthreads,
                                                 const float4* __restrict__ src,
                                                 float4* __restrict__ dst) {
    const long total = 58368L * 128;  // (B*N*T - B*N) rows * 128 float4
    long j = tid;
    for (; j + 3 * nthreads < total; j += 4 * nthreads) {
        long g0 = remap(j);
        long g1 = remap(j + nthreads);
        long g2 = remap(j + 2 * nthreads);
        long g3 = remap(j + 3 * nthreads);
        float4 v0 = src[g0], v1 = src[g1], v2 = src[g2], v3 = src[g3];
        dst[g0] = v0; dst[g1] = v1; dst[g2] = v2; dst[g3] = v3;
    }
    for (; j < total; j += nthreads) {
        long g = remap(j);
        dst[g] = src[g];
    }
}

// ---------------------------------------------------------------------------
// Fused: blocks [0,256) = one batch each: adj -> mix1 -> GEMM1 -> mix2 -> GEMM2
//        blocks [256, grid) = copy of the non-slice 120 MB
// GEMM: per wave 16m x 128n, A-frags from LDS (no barrier in K-loop),
//       B-frags gathered from global bf16 W (L2-resident, 16 rows x 64B/load)
// ---------------------------------------------------------------------------
__global__ __launch_bounds__(256) void k_fused(
    const float* __restrict__ pf, const float* __restrict__ bboxes,
    const ushort* __restrict__ wb1, const ushort* __restrict__ wb2,
    const float* __restrict__ s1v, const float* __restrict__ t1v,
    const float* __restrict__ s2v, const float* __restrict__ t2v,
    float* __restrict__ out) {
    __shared__ __align__(16) ushort xg[16 * PA];  // mix output (bf16), reused for both layers
    __shared__ float y1[16 * PY];                 // layer-1 output (f32)
    __shared__ float At[NP][NP];
    __shared__ float cxy[2][NP];
    __shared__ float rinv[NP];

    int bid = blockIdx.x, t = threadIdx.x;
    if (bid >= BB) {
        long nthreads = (long)(gridDim.x - BB) * 256;
        copy_body((long)(bid - BB) * 256 + t, nthreads, (const float4*)pf, (float4*)out);
        return;
    }

    int b = bid;
    // ---- adjacency ----
    if (t < NP) {
        const float* p = bboxes + (b * NP + t) * 4;
        cxy[0][t] = p[0] + 0.5f * p[2];
        cxy[1][t] = p[1] + 0.5f * p[3];
    }
    // zero A-garbage rows 12-15 of xg (read by MFMA lanes, never stored)
    for (int i = t; i < 4 * PA; i += 256) xg[12 * PA + i] = 0;
    __syncthreads();
    if (t < NP) {
        float s = 0.f;
        #pragma unroll
        for (int k = 0; k < NP; k++) {
            float dx = cxy[0][t] - cxy[0][k], dy = cxy[1][t] - cxy[1][k];
            s += (dx * dx + dy * dy < THR2) ? 1.f : 0.f;
        }
        rinv[t] = 1.f / (s + EPS_A);
    }
    __syncthreads();
    if (t < NP * NP) {
        int j = t / NP, n = t % NP;
        float dx = cxy[0][n] - cxy[0][j], dy = cxy[1][n] - cxy[1][j];
        float a = (dx * dx + dy * dy < THR2) ? 1.f : 0.f;
        At[j][n] = a * rinv[n];
    }
    __syncthreads();

    // ---- mix1: xg[j][c] = sum_n At[j][n] * pf[b,n,19,c] ----
    const float* xbase = pf + ((long)b * NP * TT + (TT - 1)) * DD;
    for (int c = t; c < DD; c += 256) {
        float acc[NP];
        #pragma unroll
        for (int j = 0; j < NP; j++) acc[j] = 0.f;
        #pragma unroll
        for (int n = 0; n < NP; n++) {
            float xv = xbase[(long)n * TT * DD + c];
            #pragma unroll
            for (int j = 0; j < NP; j++) acc[j] += At[j][n] * xv;
        }
        #pragma unroll
        for (int j = 0; j < NP; j++) xg[j * PA + c] = f2bf(acc[j]);
    }
    __syncthreads();

    int lane = t & 63, wave = t >> 6;
    int mrow = lane & 15, quad = lane >> 4;
    int n0w = wave * 128;
    const ushort* aptr = &xg[mrow * PA + quad * 8];

    // ---- GEMM1: y1[m][d] = relu(bn(sum_c xg[m,c]*W1[d,c])), barrier-free K-loop ----
    {
        floatx4 acc[8];
        #pragma unroll
        for (int nf = 0; nf < 8; nf++) acc[nf] = (floatx4){0.f, 0.f, 0.f, 0.f};
        const ushort* bbase = wb1 + (long)(n0w + mrow) * DD + quad * 8;
        #pragma unroll 2
        for (int kc = 0; kc < DD; kc += 32) {
            shortx8 af = *(const shortx8*)(aptr + kc);
            #pragma unroll
            for (int nf = 0; nf < 8; nf++) {
                shortx8 bf = *(const shortx8*)(bbase + (long)nf * 16 * DD + kc);
                acc[nf] = __builtin_amdgcn_mfma_f32_16x16x32_bf16(af, bf, acc[nf], 0, 0, 0);
            }
        }
        #pragma unroll
        for (int nf = 0; nf < 8; nf++) {
            int d = n0w + nf * 16 + mrow;
            float s = s1v[d], tt = t1v[d];
            #pragma unroll
            for (int v = 0; v < 4; v++) {
                int m = quad * 4 + v;
                y1[m * PY + d] = fmaxf(acc[nf][v] * s + tt, 0.f);
            }
        }
    }
    __syncthreads();

    // ---- mix2: xg[j][c] = sum_n At[j][n] * y1[n][c] ----
    for (int c = t; c < DD; c += 256) {
        float acc[NP];
        #pragma unroll
        for (int j = 0; j < NP; j++) acc[j] = 0.f;
        #pragma unroll
        for (int n = 0; n < NP; n++) {
            float xv = y1[n * PY + c];
            #pragma unroll
            for (int j = 0; j < NP; j++) acc[j] += At[j][n] * xv;
        }
        #pragma unroll
        for (int j = 0; j < NP; j++) xg[j * PA + c] = f2bf(acc[j]);
    }
    __syncthreads();

    // ---- GEMM2 -> out[b, m, 19, :] ----
    {
        floatx4 acc[8];
        #pragma unroll
        for (int nf = 0; nf < 8; nf++) acc[nf] = (floatx4){0.f, 0.f, 0.f, 0.f};
        const ushort* bbase = wb2 + (long)(n0w + mrow) * DD + quad * 8;
        #pragma unroll 2
        for (int kc = 0; kc < DD; kc += 32) {
            shortx8 af = *(const shortx8*)(aptr + kc);
            #pragma unroll
            for (int nf = 0; nf < 8; nf++) {
                shortx8 bf = *(const shortx8*)(bbase + (long)nf * 16 * DD + kc);
                acc[nf] = __builtin_amdgcn_mfma_f32_16x16x32_bf16(af, bf, acc[nf], 0, 0, 0);
            }
        }
        float* obase = out + ((long)b * NP * TT + (TT - 1)) * DD;
        #pragma unroll
        for (int nf = 0; nf < 8; nf++) {
            int d = n0w + nf * 16 + mrow;
            float s = s2v[d], tt = t2v[d];
            #pragma unroll
            for (int v = 0; v < 4; v++) {
                int m = quad * 4 + v;
                if (m < NP) obase[(long)m * TT * DD + d] = fmaxf(acc[nf][v] * s + tt, 0.f);
            }
        }
    }
}

// ---------------------------------------------------------------------------
extern "C" void kernel_launch(void* const* d_in, const int* in_sizes, int n_in,
                              void* d_out, int out_size, void* d_ws, size_t ws_size,
                              hipStream_t stream) {
    const float* pf = (const float*)d_in[0];
    const float* bboxes = (const float*)d_in[1];
    const float* W1 = (const float*)d_in[2];
    const float* b1 = (const float*)d_in[3];
    const float* g1 = (const float*)d_in[4];
    const float* beta1 = (const float*)d_in[5];
    const float* m1 = (const float*)d_in[6];
    const float* v1 = (const float*)d_in[7];
    const float* W2 = (const float*)d_in[8];
    const float* b2 = (const float*)d_in[9];
    const float* g2 = (const float*)d_in[10];
    const float* beta2 = (const float*)d_in[11];
    const float* m2 = (const float*)d_in[12];
    const float* v2 = (const float*)d_in[13];
    float* out = (float*)d_out;

    ushort* wb1 = (ushort*)d_ws;              // 262144 ushorts
    ushort* wb2 = wb1 + 262144;
    float* s1 = (float*)(wb2 + 262144);
    float* t1 = s1 + DD;
    float* s2 = t1 + DD;
    float* t2 = s2 + DD;

    k_prep<<<129, 256, 0, stream>>>(W1, W2, b1, g1, beta1, m1, v1,
                                    b2, g2, beta2, m2, v2,
                                    wb1, wb2, s1, t1, s2, t2);
    k_fused<<<BB + 768, 256, 0, stream>>>(pf, bboxes, wb1, wb2, s1, t1, s2, t2, out);
}